// Round 3
// baseline (187.647 us; speedup 1.0000x reference)
//
#include <hip/hip_runtime.h>
#include <hip/hip_bf16.h>
#include <math.h>

#define B_DIM 8
#define C_DIM 32
#define N_DIM 4096

typedef short bf16x8 __attribute__((ext_vector_type(8)));   // 8 bf16 in 4 VGPRs
typedef float f32x4 __attribute__((ext_vector_type(4)));

__device__ __forceinline__ ushort f2bf_rne(float f) {
  unsigned u = __float_as_uint(f);
  u += 0x7FFF + ((u >> 16) & 1);   // round-to-nearest-even
  return (ushort)(u >> 16);
}

// Kernel 1: cadj[b,n] = mean_c x[b,c,n]; feab[b,c,n] = bf16(x[b,c,n])
__global__ __launch_bounds__(256) void prep_kernel(const float* __restrict__ x,
                                                   float* __restrict__ cadj,
                                                   ushort* __restrict__ feab) {
  int idx = blockIdx.x * 256 + threadIdx.x;   // 0 .. B*N-1
  int b = idx >> 12;
  int n = idx & (N_DIM - 1);
  const float* p = x + (size_t)b * C_DIM * N_DIM + n;
  ushort* q = feab + (size_t)b * C_DIM * N_DIM + n;
  float s = 0.f;
#pragma unroll
  for (int c = 0; c < C_DIM; ++c) {
    float v = p[(size_t)c * N_DIM];
    s += v;
    q[(size_t)c * N_DIM] = f2bf_rne(v);
  }
  cadj[idx] = s * (1.0f / C_DIM);
}

// Kernel 2: block = 8 waves (512 thr). Block owns (16 cols) x (2 batches) x full K.
// Wave w handles K-slice [w*512, w*512+512). Partials reduced via LDS; fused epilogue.
__global__ __launch_bounds__(512, 2) void gcn_mfma_kernel(
    const ushort* __restrict__ feab, const float* __restrict__ para,
    const float* __restrict__ adj, const float* __restrict__ cadj,
    float* __restrict__ out) {
  __shared__ float part[8][1024];   // [wave][b2*512 + half*256 + reg*64 + lane]

  const int tid = threadIdx.x;
  const int lane = tid & 63;
  const int wv = tid >> 6;          // 0..7
  const int quad = lane >> 4;
  const int colgrp = blockIdx.x;    // 0..255
  const int bp = blockIdx.y;        // 0..3 -> batches 2bp, 2bp+1
  const int b0 = bp * 2;
  const int col = colgrp * 16 + (lane & 15);

  const float cm0 = cadj[b0 * N_DIM + col];
  const float cm1 = cadj[(b0 + 1) * N_DIM + col];
  const ushort* fb0 = feab + (size_t)b0 * C_DIM * N_DIM;
  const ushort* fb1 = fb0 + (size_t)C_DIM * N_DIM;
  const float* ck0 = cadj + b0 * N_DIM;
  const float* ck1 = ck0 + N_DIM;

  f32x4 acc00 = {0.f, 0.f, 0.f, 0.f};   // batch0, channels 0-15
  f32x4 acc01 = {0.f, 0.f, 0.f, 0.f};   // batch0, channels 16-31
  f32x4 acc10 = {0.f, 0.f, 0.f, 0.f};   // batch1, channels 0-15
  f32x4 acc11 = {0.f, 0.f, 0.f, 0.f};   // batch1, channels 16-31

  const int kslice0 = wv * 512;

#pragma unroll 2
  for (int ch = 0; ch < 16; ++ch) {
    const int kbase = kslice0 + ch * 32 + quad * 8;

    // adj fragment (fp32 scalars), shared by both batches
    float adjv[8];
#pragma unroll
    for (int j = 0; j < 8; ++j)
      adjv[j] = adj[(size_t)(kbase + j) * N_DIM + col];

    // cadj k-values per batch
    float ckv0[8], ckv1[8];
    *(f32x4*)&ckv0[0] = *(const f32x4*)(ck0 + kbase);
    *(f32x4*)&ckv0[4] = *(const f32x4*)(ck0 + kbase + 4);
    *(f32x4*)&ckv1[0] = *(const f32x4*)(ck1 + kbase);
    *(f32x4*)&ckv1[4] = *(const f32x4*)(ck1 + kbase + 4);

    // fea A-fragments: m=lane&15 (channel), k=quad*8+j
    const bf16x8 fa00 = *(const bf16x8*)(fb0 + (lane & 15) * N_DIM + kbase);
    const bf16x8 fa01 = *(const bf16x8*)(fb0 + (16 + (lane & 15)) * N_DIM + kbase);
    const bf16x8 fa10 = *(const bf16x8*)(fb1 + (lane & 15) * N_DIM + kbase);
    const bf16x8 fa11 = *(const bf16x8*)(fb1 + (16 + (lane & 15)) * N_DIM + kbase);

    // weight fragments: w = adj * 2t/(1+t), t=exp(-|d|)  (even in d)
    bf16x8 wf0, wf1;
#pragma unroll
    for (int j = 0; j < 8; ++j) {
      float d0 = ckv0[j] - cm0;
      float t0 = __builtin_amdgcn_exp2f(fabsf(d0) * -1.44269504f);
      float w0 = adjv[j] * (2.0f * t0 * __builtin_amdgcn_rcpf(1.0f + t0));
      wf0[j] = (short)((__float_as_uint(w0) + 0x8000u) >> 16);  // round-half-up

      float d1 = ckv1[j] - cm1;
      float t1 = __builtin_amdgcn_exp2f(fabsf(d1) * -1.44269504f);
      float w1 = adjv[j] * (2.0f * t1 * __builtin_amdgcn_rcpf(1.0f + t1));
      wf1[j] = (short)((__float_as_uint(w1) + 0x8000u) >> 16);
    }

    acc00 = __builtin_amdgcn_mfma_f32_16x16x32_bf16(fa00, wf0, acc00, 0, 0, 0);
    acc01 = __builtin_amdgcn_mfma_f32_16x16x32_bf16(fa01, wf0, acc01, 0, 0, 0);
    acc10 = __builtin_amdgcn_mfma_f32_16x16x32_bf16(fa10, wf1, acc10, 0, 0, 0);
    acc11 = __builtin_amdgcn_mfma_f32_16x16x32_bf16(fa11, wf1, acc11, 0, 0, 0);
  }

  // stash partials: slot = b2*512 + half*256 + reg*64 + lane
#pragma unroll
  for (int r = 0; r < 4; ++r) {
    part[wv][0 * 512 + 0 * 256 + r * 64 + lane] = acc00[r];
    part[wv][0 * 512 + 1 * 256 + r * 64 + lane] = acc01[r];
    part[wv][1 * 512 + 0 * 256 + r * 64 + lane] = acc10[r];
    part[wv][1 * 512 + 1 * 256 + r * 64 + lane] = acc11[r];
  }
  __syncthreads();

  // reduce across waves + epilogue: 2 outputs per thread
#pragma unroll
  for (int pass = 0; pass < 2; ++pass) {
    const int e = tid + pass * 512;
    float s = 0.f;
#pragma unroll
    for (int ww = 0; ww < 8; ++ww) s += part[ww][e];
    const int lane_e = e & 63;
    const int reg = (e >> 6) & 3;
    const int half = (e >> 8) & 1;
    const int b2 = e >> 9;
    const int c = half * 16 + (lane_e >> 4) * 4 + reg;
    const int ocol = colgrp * 16 + (lane_e & 15);
    const float v = s * para[(size_t)c * N_DIM + ocol];
    out[((size_t)((b0 + b2) * C_DIM + c)) * N_DIM + ocol] = fmaxf(v, 0.f);
  }
}

extern "C" void kernel_launch(void* const* d_in, const int* in_sizes, int n_in,
                              void* d_out, int out_size, void* d_ws, size_t ws_size,
                              hipStream_t stream) {
  const float* x = (const float*)d_in[0];     // [8,32,64,64]
  const float* para = (const float*)d_in[1];  // [1,32,64,64]
  const float* adj = (const float*)d_in[2];   // [4096,4096]
  float* out = (float*)d_out;

  float* cadj = (float*)d_ws;                                 // 8*4096 f32 = 128 KB
  ushort* feab = (ushort*)((char*)d_ws + B_DIM * N_DIM * 4);  // 8*32*4096 bf16 = 2 MB

  prep_kernel<<<dim3(B_DIM * N_DIM / 256), dim3(256), 0, stream>>>(x, cadj, feab);
  gcn_mfma_kernel<<<dim3(N_DIM / 16, B_DIM / 2), dim3(512), 0, stream>>>(feab, para, adj, cadj, out);
}